// Round 12
// baseline (538.982 us; speedup 1.0000x reference)
//
#include <hip/hip_runtime.h>

#define LOG2E      1.44269504088896340736f
#define TWO_LOG2E  2.88539008177792680472f

typedef float f2   __attribute__((ext_vector_type(2)));
typedef float f16v __attribute__((ext_vector_type(16)));
typedef unsigned long long ull;

// async global->LDS, 16B per lane. LDS dest = wave-uniform base + lane*16.
__device__ __forceinline__ void gload_lds16(const float* g, float* l) {
    auto gp = (const __attribute__((address_space(1))) float*)g;
    auto lp = (__attribute__((address_space(3))) float*)l;
    __builtin_amdgcn_global_load_lds(gp, lp, 16, 0, 0);
}

// Layout (all fp32):
//   images [32,1024,64,16] -> off(n,b,s,d) = n*1048576 + b*1024 + s*16 + d
//   out    [32,1024,64,16] -> same
// TWO chains per wave (b0=2w, b1=b0+1). This round: the two chains'
// instructions are interleaved A,B,A,B at INSTRUCTION granularity inside
// three fused asm blocks per step-pair (DOT2 / ACT2 / CUP2), so chain B's
// instruction always sits in chain A's dependency-latency slot (waves are
// in-order; R9/R11 showed block-atomic asm can't share stalls: 650 cyc/pair
// vs ~180 cyc serial chain).
// ROW-MAJOR lane map per chain: row a = lane>>4, pos j = lane&15; gate
// mapping probed at runtime; weight row = gate*16+j (torch i,f,g,o).
// Recurrent dot = 16 DPP row_ror fmacs per chain (accumulator reuse distance
// 4 after interleave). Gates gathered via permlane16/32_swap. Weights/bias
// pre-scaled by each activation's exp2 coefficient; tanh gate folds K=2log2e
// so c' = K*c is tracked.
// x data path: per half-phase 4x s_load_dwordx16 (SMEM pipe) into 64 SGPRs
// (R9/R11-verified addressing); PROJ = 8 v_pk_fma_f32 with SGPR-pair src0.
// x latency path: chunk n+2 (8 KB) pulled through L2 ~17 phases early via 8
// global_load_lds into write-only LDS scratch (R8-proven: FETCH 131->65.6MB).

__global__ __launch_bounds__(256, 1)
void lstm_fused(const float* __restrict__ images,
                const float* __restrict__ w_ih,
                const float* __restrict__ w_hh,
                const float* __restrict__ b_ih,
                const float* __restrict__ b_hh,
                float* __restrict__ out)
{
    __shared__ float4 warm[4][256];   // 4 KB/wave write-only L2-warm scratch

    const int lane = threadIdx.x & 63;
    const int wid  = threadIdx.x >> 6;
    const int w    = (blockIdx.x << 2) + wid;   // 0..511
    const int b0   = w << 1;                    // chain A; chain B = b0+1
    const int a    = lane >> 4;                 // row 0..3
    const int j    = lane & 15;                 // unit 0..15

    asm volatile("" :: "v"(&warm[wid][0]) : "memory");

    // ---- runtime convention probes (init-only; verified passing R4-R11) ----
    int rr1 = __builtin_amdgcn_update_dpp(0, j, 0x121, 0xF, 0xF, true);
    const int d_ror = (rr1 - j) & 15;           // src pos of ror:t = (j + d_ror*t)&15

    int e16;
    { int pa = a, pb = a;
      asm volatile("s_nop 1\n\t"
                   "v_permlane16_swap_b32 %0, %1" : "+v"(pa), "+v"(pb));
      e16 = pa & 1; }
    int e32;
    { int pc = a, pd = a;
      asm volatile("s_nop 1\n\t"
                   "v_permlane32_swap_b32 %0, %1" : "+v"(pc), "+v"(pd));
      e32 = (pc < 2) ? 0 : 1; }

    const int m1 = ((a >> 1) == e32);
    const int m0 = ((a & 1) == e16);
    const int gate = m0 ? (m1 ? 1 : 2) : (m1 ? 0 : 3);  // torch: i=0,f=1,g=2,o=3
    const int r = gate * 16 + j;

    const float aa = (gate == 2) ? TWO_LOG2E : -LOG2E;
    const float mm = (gate == 2) ? -2.0f * TWO_LOG2E : 1.0f;
    const float dd = (gate == 2) ? TWO_LOG2E : 0.0f;

    // recurrent weights, slot t matches row_ror:t source pos
    float whh[16];
#pragma unroll
    for (int t = 0; t < 16; ++t)
        whh[t] = aa * w_hh[r * 16 + ((j + d_ror * t) & 15)];
    f2 wihp[8];
#pragma unroll
    for (int m = 0; m < 8; ++m) {
        f2 wv; wv.x = aa * w_ih[r * 16 + 2 * m]; wv.y = aa * w_ih[r * 16 + 2 * m + 1];
        wihp[m] = wv;
    }
    const float bias = aa * (b_ih[r] + b_hh[r]);

    const bool su0 = (a == 0), su1 = (a == 1), su2 = (a == 2), su3 = (a == 3);

    float hvA = 0.0f, cA = 0.0f, svA = 0.0f;
    float hvB = 0.0f, cB = 0.0f, svB = 0.0f;

    const int bbA = b0 << 10;
    const int bbB = bbA + 1024;
    const unsigned wb = __builtin_amdgcn_readfirstlane(b0);
    const ull img_u = (ull)images;

#define PBC(p, bb) ((((p) >> 4) << 20) + (bb) + (((((p) << 2)) & 63) << 4))

#define WARM_CHUNK(n) {                                                        \
        const float* gp_ = images + ((n) << 20) + bbA + (lane << 2);           \
        float4* lb_ = &warm[wid][0];                                           \
        gload_lds16(gp_ + 0,    (float*)(lb_ + 0));                            \
        gload_lds16(gp_ + 256,  (float*)(lb_ + 64));                           \
        gload_lds16(gp_ + 512,  (float*)(lb_ + 128));                          \
        gload_lds16(gp_ + 768,  (float*)(lb_ + 192));                          \
        gload_lds16(gp_ + 1024, (float*)(lb_ + 0));                            \
        gload_lds16(gp_ + 1280, (float*)(lb_ + 64));                           \
        gload_lds16(gp_ + 1536, (float*)(lb_ + 128));                          \
        gload_lds16(gp_ + 1792, (float*)(lb_ + 192)); }

#define SLOAD2(HPraw) {                                                        \
        int hp_ = (HPraw); if (hp_ > 1023) hp_ = 1023;                         \
        ull sb_ = img_u + ((ull)(hp_ >> 5) << 22) + ((ull)wb << 12)            \
                        + (ull)((hp_ & 31) << 7);                              \
        asm volatile("s_load_dwordx16 %0, %4, 0x0\n\t"                         \
                     "s_load_dwordx16 %1, %4, 0x40\n\t"                        \
                     "s_load_dwordx16 %2, %4, 0x1000\n\t"                      \
                     "s_load_dwordx16 %3, %4, 0x1040"                          \
                     : "=s"(sxA), "=s"(sxA1), "=s"(sxB), "=s"(sxB1)            \
                     : "s"(sb_));                                              \
    }

#define WAIT_LGKM() { asm volatile("s_waitcnt lgkmcnt(0)" ::: "memory");       \
                      __builtin_amdgcn_sched_barrier(0); }

#define PROJPK(dst, sxv) {                                                     \
        f2 A_;                                                                 \
        { f2 x_ = {sxv[0],  sxv[1]};                                           \
          asm("v_pk_mul_f32 %0, %1, %2"     : "=v"(A_) : "s"(x_), "v"(wihp[0])); } \
        { f2 x_ = {sxv[2],  sxv[3]};                                           \
          asm("v_pk_fma_f32 %0, %1, %2, %0" : "+v"(A_) : "s"(x_), "v"(wihp[1])); } \
        { f2 x_ = {sxv[4],  sxv[5]};                                           \
          asm("v_pk_fma_f32 %0, %1, %2, %0" : "+v"(A_) : "s"(x_), "v"(wihp[2])); } \
        { f2 x_ = {sxv[6],  sxv[7]};                                           \
          asm("v_pk_fma_f32 %0, %1, %2, %0" : "+v"(A_) : "s"(x_), "v"(wihp[3])); } \
        { f2 x_ = {sxv[8],  sxv[9]};                                           \
          asm("v_pk_fma_f32 %0, %1, %2, %0" : "+v"(A_) : "s"(x_), "v"(wihp[4])); } \
        { f2 x_ = {sxv[10], sxv[11]};                                          \
          asm("v_pk_fma_f32 %0, %1, %2, %0" : "+v"(A_) : "s"(x_), "v"(wihp[5])); } \
        { f2 x_ = {sxv[12], sxv[13]};                                          \
          asm("v_pk_fma_f32 %0, %1, %2, %0" : "+v"(A_) : "s"(x_), "v"(wihp[6])); } \
        { f2 x_ = {sxv[14], sxv[15]};                                          \
          asm("v_pk_fma_f32 %0, %1, %2, %0" : "+v"(A_) : "s"(x_), "v"(wihp[7])); } \
        dst = A_.x + A_.y;                                                     \
    }

    // ---- fused step-pair: A/B interleaved at instruction granularity ----
#define STEPPAIR(SU, xpa, xpb) {                                               \
        float a0 = (xpa), a1 = bias, b0 = (xpb), b1 = bias;                    \
        /* DOT2: 32 fmacs, A,B alternating; acc reuse distance 4 */            \
        asm("s_nop 1\n\t"                                                      \
          "v_fmac_f32 %[a0], %[hA], %[w0]\n\t"                                 \
          "v_fmac_f32 %[b0], %[hB], %[w0]\n\t"                                 \
          "v_fmac_f32 %[a1], %[hA], %[w1] row_ror:1 row_mask:0xf bank_mask:0xf\n\t" \
          "v_fmac_f32 %[b1], %[hB], %[w1] row_ror:1 row_mask:0xf bank_mask:0xf\n\t" \
          "v_fmac_f32 %[a0], %[hA], %[w2] row_ror:2 row_mask:0xf bank_mask:0xf\n\t" \
          "v_fmac_f32 %[b0], %[hB], %[w2] row_ror:2 row_mask:0xf bank_mask:0xf\n\t" \
          "v_fmac_f32 %[a1], %[hA], %[w3] row_ror:3 row_mask:0xf bank_mask:0xf\n\t" \
          "v_fmac_f32 %[b1], %[hB], %[w3] row_ror:3 row_mask:0xf bank_mask:0xf\n\t" \
          "v_fmac_f32 %[a0], %[hA], %[w4] row_ror:4 row_mask:0xf bank_mask:0xf\n\t" \
          "v_fmac_f32 %[b0], %[hB], %[w4] row_ror:4 row_mask:0xf bank_mask:0xf\n\t" \
          "v_fmac_f32 %[a1], %[hA], %[w5] row_ror:5 row_mask:0xf bank_mask:0xf\n\t" \
          "v_fmac_f32 %[b1], %[hB], %[w5] row_ror:5 row_mask:0xf bank_mask:0xf\n\t" \
          "v_fmac_f32 %[a0], %[hA], %[w6] row_ror:6 row_mask:0xf bank_mask:0xf\n\t" \
          "v_fmac_f32 %[b0], %[hB], %[w6] row_ror:6 row_mask:0xf bank_mask:0xf\n\t" \
          "v_fmac_f32 %[a1], %[hA], %[w7] row_ror:7 row_mask:0xf bank_mask:0xf\n\t" \
          "v_fmac_f32 %[b1], %[hB], %[w7] row_ror:7 row_mask:0xf bank_mask:0xf\n\t" \
          "v_fmac_f32 %[a0], %[hA], %[w8] row_ror:8 row_mask:0xf bank_mask:0xf\n\t" \
          "v_fmac_f32 %[b0], %[hB], %[w8] row_ror:8 row_mask:0xf bank_mask:0xf\n\t" \
          "v_fmac_f32 %[a1], %[hA], %[w9] row_ror:9 row_mask:0xf bank_mask:0xf\n\t" \
          "v_fmac_f32 %[b1], %[hB], %[w9] row_ror:9 row_mask:0xf bank_mask:0xf\n\t" \
          "v_fmac_f32 %[a0], %[hA], %[w10] row_ror:10 row_mask:0xf bank_mask:0xf\n\t" \
          "v_fmac_f32 %[b0], %[hB], %[w10] row_ror:10 row_mask:0xf bank_mask:0xf\n\t" \
          "v_fmac_f32 %[a1], %[hA], %[w11] row_ror:11 row_mask:0xf bank_mask:0xf\n\t" \
          "v_fmac_f32 %[b1], %[hB], %[w11] row_ror:11 row_mask:0xf bank_mask:0xf\n\t" \
          "v_fmac_f32 %[a0], %[hA], %[w12] row_ror:12 row_mask:0xf bank_mask:0xf\n\t" \
          "v_fmac_f32 %[b0], %[hB], %[w12] row_ror:12 row_mask:0xf bank_mask:0xf\n\t" \
          "v_fmac_f32 %[a1], %[hA], %[w13] row_ror:13 row_mask:0xf bank_mask:0xf\n\t" \
          "v_fmac_f32 %[b1], %[hB], %[w13] row_ror:13 row_mask:0xf bank_mask:0xf\n\t" \
          "v_fmac_f32 %[a0], %[hA], %[w14] row_ror:14 row_mask:0xf bank_mask:0xf\n\t" \
          "v_fmac_f32 %[b0], %[hB], %[w14] row_ror:14 row_mask:0xf bank_mask:0xf\n\t" \
          "v_fmac_f32 %[a1], %[hA], %[w15] row_ror:15 row_mask:0xf bank_mask:0xf\n\t" \
          "v_fmac_f32 %[b1], %[hB], %[w15] row_ror:15 row_mask:0xf bank_mask:0xf"   \
          : [a0]"+v"(a0), [a1]"+v"(a1), [b0]"+v"(b0), [b1]"+v"(b1)             \
          : [hA]"v"(hvA), [hB]"v"(hvB),                                        \
            [w0]"v"(whh[0]),  [w1]"v"(whh[1]),  [w2]"v"(whh[2]),  [w3]"v"(whh[3]), \
            [w4]"v"(whh[4]),  [w5]"v"(whh[5]),  [w6]"v"(whh[6]),  [w7]"v"(whh[7]), \
            [w8]"v"(whh[8]),  [w9]"v"(whh[9]),  [w10]"v"(whh[10]),[w11]"v"(whh[11]),\
            [w12]"v"(whh[12]),[w13]"v"(whh[13]),[w14]"v"(whh[14]),[w15]"v"(whh[15]));\
        float gA0, gA1, gA2, gA3, gB0, gB1, gB2, gB3, tA, tB;                  \
        /* ACT2: act + gather, A/B interleaved */                              \
        asm("v_add_f32 %[tA], %[a0], %[a1]\n\t"                                \
          "v_add_f32 %[tB], %[b0], %[b1]\n\t"                                  \
          "v_exp_f32 %[tA], %[tA]\n\t"                                         \
          "v_exp_f32 %[tB], %[tB]\n\t"                                         \
          "v_add_f32 %[tA], 1.0, %[tA]\n\t"                                    \
          "v_add_f32 %[tB], 1.0, %[tB]\n\t"                                    \
          "v_rcp_f32 %[tA], %[tA]\n\t"                                         \
          "v_rcp_f32 %[tB], %[tB]\n\t"                                         \
          "v_fma_f32 %[gA0], %[mm], %[tA], %[dd]\n\t"                          \
          "v_fma_f32 %[gB0], %[mm], %[tB], %[dd]\n\t"                          \
          "v_mov_b32 %[gA1], %[gA0]\n\t"                                       \
          "v_mov_b32 %[gB1], %[gB0]\n\t"                                       \
          "s_nop 1\n\t"                                                        \
          "v_permlane16_swap_b32 %[gA0], %[gA1]\n\t"                           \
          "v_permlane16_swap_b32 %[gB0], %[gB1]\n\t"                           \
          "v_mov_b32 %[gA2], %[gA0]\n\t"                                       \
          "v_mov_b32 %[gA3], %[gA1]\n\t"                                       \
          "v_mov_b32 %[gB2], %[gB0]\n\t"                                       \
          "v_mov_b32 %[gB3], %[gB1]\n\t"                                       \
          "v_permlane32_swap_b32 %[gA0], %[gA2]\n\t"                           \
          "v_permlane32_swap_b32 %[gB0], %[gB2]\n\t"                           \
          "v_permlane32_swap_b32 %[gA1], %[gA3]\n\t"                           \
          "v_permlane32_swap_b32 %[gB1], %[gB3]"                               \
          : [gA0]"=&v"(gA0), [gA1]"=&v"(gA1), [gA2]"=&v"(gA2), [gA3]"=&v"(gA3),\
            [gB0]"=&v"(gB0), [gB1]"=&v"(gB1), [gB2]"=&v"(gB2), [gB3]"=&v"(gB3),\
            [tA]"=&v"(tA), [tB]"=&v"(tB)                                       \
          : [a0]"v"(a0), [a1]"v"(a1), [b0]"v"(b0), [b1]"v"(b1),                \
            [mm]"v"(mm), [dd]"v"(dd));                                         \
        /* CUP2: c-update + tanh + h, A/B interleaved. qf=g0 qi=g1 qg=g2 qo=g3 */ \
        float igA, igB, o2A, o2B, uA, uB;                                      \
        asm("v_mul_f32 %[igA], %[gA1], %[gA2]\n\t"                             \
          "v_mul_f32 %[igB], %[gB1], %[gB2]\n\t"                               \
          "v_add_f32 %[o2A], %[gA3], %[gA3]\n\t"                               \
          "v_add_f32 %[o2B], %[gB3], %[gB3]\n\t"                               \
          "v_fma_f32 %[cA], %[cA], %[gA0], %[igA]\n\t"                         \
          "v_fma_f32 %[cB], %[cB], %[gB0], %[igB]\n\t"                         \
          "v_exp_f32 %[uA], %[cA]\n\t"                                         \
          "v_exp_f32 %[uB], %[cB]\n\t"                                         \
          "v_add_f32 %[uA], 1.0, %[uA]\n\t"                                    \
          "v_add_f32 %[uB], 1.0, %[uB]\n\t"                                    \
          "v_rcp_f32 %[uA], %[uA]\n\t"                                         \
          "v_rcp_f32 %[uB], %[uB]\n\t"                                         \
          "v_fma_f32 %[hA], %[o2A], -%[uA], %[gA3]\n\t"                        \
          "v_fma_f32 %[hB], %[o2B], -%[uB], %[gB3]"                            \
          : [cA]"+v"(cA), [cB]"+v"(cB), [hA]"=&v"(hvA), [hB]"=&v"(hvB),        \
            [igA]"=&v"(igA), [igB]"=&v"(igB), [o2A]"=&v"(o2A), [o2B]"=&v"(o2B),\
            [uA]"=&v"(uA), [uB]"=&v"(uB)                                       \
          : [gA0]"v"(gA0), [gA1]"v"(gA1), [gA2]"v"(gA2), [gA3]"v"(gA3),        \
            [gB0]"v"(gB0), [gB1]"v"(gB1), [gB2]"v"(gB2), [gB3]"v"(gB3));       \
        svA = (SU) ? hvA : svA;                                                \
        svB = (SU) ? hvB : svB;                                                \
    }

    f16v  sxA, sxA1, sxB, sxB1;   // 64-SGPR x buffer (half-phase, 2 chains)
    float xpA[4], xpB[4];

    // prologue: warm chunks 0,1; load+project half-phase 0; launch hp 1
    WARM_CHUNK(0);
    WARM_CHUNK(1);
    SLOAD2(0);
    WAIT_LGKM();
    PROJPK(xpA[0], sxA); PROJPK(xpA[1], sxA1);
    PROJPK(xpB[0], sxB); PROJPK(xpB[1], sxB1);
    SLOAD2(1);

#pragma unroll 1
    for (int P = 0; P < 512; ++P) {
        STEPPAIR(su0, xpA[0], xpB[0]);        // step 4P
        STEPPAIR(su1, xpA[1], xpB[1]);        // step 4P+1
        WAIT_LGKM();                          // drain SLOAD2(2P+1)
        PROJPK(xpA[2], sxA); PROJPK(xpA[3], sxA1);
        PROJPK(xpB[2], sxB); PROJPK(xpB[3], sxB1);
        SLOAD2(2 * P + 2);                    // steps 4P+4,4P+5
        STEPPAIR(su2, xpA[2], xpB[2]);        // step 4P+2
        STEPPAIR(su3, xpA[3], xpB[3]);        // step 4P+3
        out[PBC(P, bbA) + lane] = svA;        // coalesced 256B per chain
        out[PBC(P, bbB) + lane] = svB;
        if ((P & 15) == 14 && P < 480)
            WARM_CHUNK((P >> 4) + 2);         // pull chunk+2 through L2 early
        WAIT_LGKM();                          // drain SLOAD2(2P+2)
        PROJPK(xpA[0], sxA); PROJPK(xpA[1], sxA1);
        PROJPK(xpB[0], sxB); PROJPK(xpB[1], sxB1);
        SLOAD2(2 * P + 3);                    // steps 4P+6,4P+7
    }

#undef STEPPAIR
#undef PROJPK
#undef WAIT_LGKM
#undef SLOAD2
#undef WARM_CHUNK
#undef PBC
}

extern "C" void kernel_launch(void* const* d_in, const int* in_sizes, int n_in,
                              void* d_out, int out_size, void* d_ws, size_t ws_size,
                              hipStream_t stream)
{
    const float* images = (const float*)d_in[0];
    const float* w_ih   = (const float*)d_in[1];
    const float* w_hh   = (const float*)d_in[2];
    const float* b_ih   = (const float*)d_in[3];
    const float* b_hh   = (const float*)d_in[4];
    float* outp         = (float*)d_out;

    lstm_fused<<<dim3(128), dim3(256), 0, stream>>>(images, w_ih, w_hh, b_ih, b_hh, outp);
}

// Round 13
// 468.804 us; speedup vs baseline: 1.1497x; 1.1497x over previous
//
#include <hip/hip_runtime.h>

#define LOG2E      1.44269504088896340736f
#define TWO_LOG2E  2.88539008177792680472f

typedef float f2 __attribute__((ext_vector_type(2)));

__device__ __forceinline__ float frcp(float x)  { return __builtin_amdgcn_rcpf(x); }
__device__ __forceinline__ float fexp2(float x) { return __builtin_amdgcn_exp2f(x); }

__device__ __forceinline__ f2 pk_mul(f2 a, f2 b) {
    f2 d; asm("v_pk_mul_f32 %0, %1, %2" : "=v"(d) : "v"(a), "v"(b)); return d;
}
__device__ __forceinline__ f2 pk_fma(f2 a, f2 b, f2 c) {
    f2 d; asm("v_pk_fma_f32 %0, %1, %2, %3" : "=v"(d) : "v"(a), "v"(b), "v"(c)); return d;
}
__device__ __forceinline__ f2 pk_add(f2 a, f2 b) {
    f2 d; asm("v_pk_add_f32 %0, %1, %2" : "=v"(d) : "v"(a), "v"(b)); return d;
}
__device__ __forceinline__ f2 f2lo(float4 v) { f2 r; r.x = v.x; r.y = v.y; return r; }
__device__ __forceinline__ f2 f2hi(float4 v) { f2 r; r.x = v.z; r.y = v.w; return r; }

// async global->LDS, 16B per lane. LDS dest = wave-uniform base + lane*16.
__device__ __forceinline__ void gload_lds16(const float* g, float* l) {
    auto gp = (const __attribute__((address_space(1))) float*)g;
    auto lp = (__attribute__((address_space(3))) float*)l;
    __builtin_amdgcn_global_load_lds(gp, lp, 16, 0, 0);
}

// EXACT R5 champion kernel (292 us); single variable changed this round:
// launch geometry. 512-thread blocks (8 waves = 8 chains) x 128 blocks
// -> 1024 waves packed TWO PER SIMD on 128 CUs (vs 1/SIMD on 256 CUs).
// Theory: per-wave issue cadence (~4cyc/instr plain, ~9 DPP, ~16 trans) is a
// WAVE slot limit, not a SIMD limit (m07: 65% of VALU peak > the 50% a
// 1-instr/4cyc/SIMD cap would allow). Two co-resident waves should interleave
// issue slots and nearly halve wall time per step. If instead the SIMD caps
// at 1 instr/4cyc total, this costs ~15-30% -- decisive either way.

__global__ __launch_bounds__(512, 1)
void lstm_fused(const float* __restrict__ images,
                const float* __restrict__ w_ih,
                const float* __restrict__ w_hh,
                const float* __restrict__ b_ih,
                const float* __restrict__ b_hh,
                float* __restrict__ out)
{
    __shared__ float4 xlds[8][2][256];   // [wave][buf][1 KB as float4] = 64 KB

    const int lane = threadIdx.x & 63;
    const int wid  = threadIdx.x >> 6;          // 0..7
    const int b    = (blockIdx.x << 3) + wid;   // 0..1023
    const int a    = lane >> 4;                 // row 0..3
    const int j    = lane & 15;                 // unit 0..15

    // ---- runtime convention probes (init-only; verified passing R4-R12) ----
    int rr1 = __builtin_amdgcn_update_dpp(0, j, 0x121, 0xF, 0xF, true);
    const int d_ror = (rr1 - j) & 15;           // src pos of ror:t = (j + d_ror*t)&15

    int e16;
    { int pa = a, pb = a;
      asm volatile("s_nop 1\n\t"
                   "v_permlane16_swap_b32 %0, %1" : "+v"(pa), "+v"(pb));
      e16 = pa & 1; }
    int e32;
    { int pc = a, pd = a;
      asm volatile("s_nop 1\n\t"
                   "v_permlane32_swap_b32 %0, %1" : "+v"(pc), "+v"(pd));
      e32 = (pc < 2) ? 0 : 1; }

    const int m1 = ((a >> 1) == e32);
    const int m0 = ((a & 1) == e16);
    const int gate = m0 ? (m1 ? 1 : 2) : (m1 ? 0 : 3);  // torch: i=0,f=1,g=2,o=3
    const int r = gate * 16 + j;

    const float aa = (gate == 2) ? TWO_LOG2E : -LOG2E;
    const float mm = (gate == 2) ? -2.0f * TWO_LOG2E : 1.0f;
    const float dd = (gate == 2) ? TWO_LOG2E : 0.0f;

    float whh[16];
#pragma unroll
    for (int t = 0; t < 16; ++t)
        whh[t] = aa * w_hh[r * 16 + ((j + d_ror * t) & 15)];
    f2 wihp[8];
#pragma unroll
    for (int m = 0; m < 8; ++m) {
        f2 w; w.x = aa * w_ih[r * 16 + 2 * m]; w.y = aa * w_ih[r * 16 + 2 * m + 1];
        wihp[m] = w;
    }
    const float bias = aa * (b_ih[r] + b_hh[r]);

    // hoisted store-select masks (one v_cmp each, off the serial path)
    const bool su0 = (a == 0), su1 = (a == 1), su2 = (a == 2), su3 = (a == 3);

    float hv = 0.0f;   // h[j], replicated across rows
    float c  = 0.0f;   // K * c_true
    float sv = 0.0f;   // per-phase store value (row a holds step a)

    const int bbase = b << 10;  // b*1024

#define PB(p) ((((p) >> 4) << 20) + bbase + (((((p) << 2)) & 63) << 4))

#define GLOAD_CHUNK(n) {                                                       \
        const float* gp_ = images + ((n) << 20) + bbase + (lane << 2);         \
        float4* lb_ = &xlds[wid][(n) & 1][0];                                  \
        gload_lds16(gp_ + 0,   (float*)(lb_ + 0));                             \
        gload_lds16(gp_ + 256, (float*)(lb_ + 64));                            \
        gload_lds16(gp_ + 512, (float*)(lb_ + 128));                           \
        gload_lds16(gp_ + 768, (float*)(lb_ + 192)); }

    // PINNED issue of phase Q's 16 uniform ds_read_b128 into xv (volatile).
#define DSREADV(xv, Qraw) {                                                    \
        int Q_ = (Qraw); if (Q_ > 511) Q_ = 511;                               \
        auto lp_ = (const __attribute__((address_space(3))) float4*)           \
                   &xlds[wid][(Q_ >> 4) & 1][(Q_ & 15) << 4];                  \
        _Pragma("unroll")                                                      \
        for (int q = 0; q < 16; ++q)                                           \
            asm volatile("ds_read_b128 %0, %1 offset:%2"                       \
                : "=v"(xv[q]) : "v"(lp_), "i"(q * 16) : "memory");             \
    }

#define WAIT_LGKM() { asm volatile("s_waitcnt lgkmcnt(0)" ::: "memory");       \
                      __builtin_amdgcn_sched_barrier(0); }

    // xpre[u] = scaled bias + dot(scaled w_ih, x_t), packed-fp32
#define PROJ(xpre, xv) {                                                       \
        _Pragma("unroll")                                                      \
        for (int u = 0; u < 4; ++u) {                                          \
            f2 A_ = pk_mul(wihp[0], f2lo(xv[4*u+0]));                          \
            f2 B_ = pk_mul(wihp[1], f2hi(xv[4*u+0]));                          \
            A_ = pk_fma(wihp[2], f2lo(xv[4*u+1]), A_);                         \
            B_ = pk_fma(wihp[3], f2hi(xv[4*u+1]), B_);                         \
            A_ = pk_fma(wihp[4], f2lo(xv[4*u+2]), A_);                         \
            B_ = pk_fma(wihp[5], f2hi(xv[4*u+2]), B_);                         \
            A_ = pk_fma(wihp[6], f2lo(xv[4*u+3]), A_);                         \
            B_ = pk_fma(wihp[7], f2hi(xv[4*u+3]), B_);                         \
            A_ = pk_add(A_, B_);                                               \
            xpre[u] = (bias + A_.x) + A_.y;                                    \
        } }

    // one recurrence step; dot + gather asm are NON-volatile (pure dataflow)
#define STEP(SU, xpv) {                                                        \
        float p0 = (xpv), p1, p2, p3;                                          \
        asm("s_nop 1\n\t"                                                      \
          "v_fmac_f32 %[q0], %[h], %[w0]\n\t"                                  \
          "v_mul_f32 %[q1], %[h], %[w1] row_ror:1 row_mask:0xf bank_mask:0xf\n\t" \
          "v_mul_f32 %[q2], %[h], %[w2] row_ror:2 row_mask:0xf bank_mask:0xf\n\t" \
          "v_mul_f32 %[q3], %[h], %[w3] row_ror:3 row_mask:0xf bank_mask:0xf\n\t" \
          "v_fmac_f32 %[q0], %[h], %[w4] row_ror:4 row_mask:0xf bank_mask:0xf\n\t" \
          "v_fmac_f32 %[q1], %[h], %[w5] row_ror:5 row_mask:0xf bank_mask:0xf\n\t" \
          "v_fmac_f32 %[q2], %[h], %[w6] row_ror:6 row_mask:0xf bank_mask:0xf\n\t" \
          "v_fmac_f32 %[q3], %[h], %[w7] row_ror:7 row_mask:0xf bank_mask:0xf\n\t" \
          "v_fmac_f32 %[q0], %[h], %[w8] row_ror:8 row_mask:0xf bank_mask:0xf\n\t" \
          "v_fmac_f32 %[q1], %[h], %[w9] row_ror:9 row_mask:0xf bank_mask:0xf\n\t" \
          "v_fmac_f32 %[q2], %[h], %[w10] row_ror:10 row_mask:0xf bank_mask:0xf\n\t" \
          "v_fmac_f32 %[q3], %[h], %[w11] row_ror:11 row_mask:0xf bank_mask:0xf\n\t" \
          "v_fmac_f32 %[q0], %[h], %[w12] row_ror:12 row_mask:0xf bank_mask:0xf\n\t" \
          "v_fmac_f32 %[q1], %[h], %[w13] row_ror:13 row_mask:0xf bank_mask:0xf\n\t" \
          "v_fmac_f32 %[q2], %[h], %[w14] row_ror:14 row_mask:0xf bank_mask:0xf\n\t" \
          "v_fmac_f32 %[q3], %[h], %[w15] row_ror:15 row_mask:0xf bank_mask:0xf"   \
          : [q0]"+v"(p0), [q1]"=&v"(p1), [q2]"=&v"(p2), [q3]"=&v"(p3)          \
          : [h]"v"(hv),                                                        \
            [w0]"v"(whh[0]),  [w1]"v"(whh[1]),  [w2]"v"(whh[2]),  [w3]"v"(whh[3]), \
            [w4]"v"(whh[4]),  [w5]"v"(whh[5]),  [w6]"v"(whh[6]),  [w7]"v"(whh[7]), \
            [w8]"v"(whh[8]),  [w9]"v"(whh[9]),  [w10]"v"(whh[10]),[w11]"v"(whh[11]),\
            [w12]"v"(whh[12]),[w13]"v"(whh[13]),[w14]"v"(whh[14]),[w15]"v"(whh[15]));\
        float arg = (p0 + p1) + (p2 + p3);                                     \
        float act = fmaf(mm, frcp(1.0f + fexp2(arg)), dd);                     \
        float qf, qg, qi, qo;                                                  \
        asm("v_mov_b32 %[A], %[x]\n\t"                                         \
          "v_mov_b32 %[B], %[x]\n\t"                                           \
          "s_nop 1\n\t"                                                        \
          "v_permlane16_swap_b32 %[A], %[B]\n\t"                               \
          "v_mov_b32 %[C], %[A]\n\t"                                           \
          "v_mov_b32 %[D], %[B]\n\t"                                           \
          "v_permlane32_swap_b32 %[A], %[C]\n\t"                               \
          "v_permlane32_swap_b32 %[B], %[D]"                                   \
          : [A]"=&v"(qf), [B]"=&v"(qi), [C]"=&v"(qg), [D]"=&v"(qo)             \
          : [x]"v"(act));                                                      \
        float ig = qi * qg;                                                    \
        float qo2 = qo + qo;                                                   \
        c = fmaf(c, qf, ig);                                                   \
        float rr = frcp(1.0f + fexp2(c));                                      \
        hv = fmaf(-qo2, rr, qo);                                               \
        sv = (SU) ? hv : sv;                                                   \
    }

#define STORE(pb) out[(pb) + lane] = sv;

    float4 xv[16];
    float  xpre[4];

    // prologue: stage chunks 0,1; prime phase 0
    GLOAD_CHUNK(0);
    GLOAD_CHUNK(1);
    asm volatile("s_waitcnt vmcnt(0)" ::: "memory");
    DSREADV(xv, 0);
    WAIT_LGKM();
    PROJ(xpre, xv);

#pragma unroll 1
    for (int P = 0; P < 512; ++P) {
        DSREADV(xv, P + 1);                // pinned early issue (phase P+1)
        {
            const int pb = PB(P);
            STEP(su0, xpre[0]);
            STEP(su1, xpre[1]);
            STEP(su2, xpre[2]);
            STEP(su3, xpre[3]);
            STORE(pb);
        }
        if ((P & 15) == 8)                 // chunk staging guaranteed done
            asm volatile("s_waitcnt vmcnt(0)" ::: "memory");
        WAIT_LGKM();                       // drain this iter's 16 ds_reads
        PROJ(xpre, xv);                    // phase P+1
        if ((P & 15) == 14 && P < 480)
            GLOAD_CHUNK((P >> 4) + 2);     // stage chunk+2, ~16 phases early
    }

#undef STEP
#undef STORE
#undef PROJ
#undef WAIT_LGKM
#undef DSREADV
#undef GLOAD_CHUNK
#undef PB
}

extern "C" void kernel_launch(void* const* d_in, const int* in_sizes, int n_in,
                              void* d_out, int out_size, void* d_ws, size_t ws_size,
                              hipStream_t stream)
{
    const float* images = (const float*)d_in[0];
    const float* w_ih   = (const float*)d_in[1];
    const float* w_hh   = (const float*)d_in[2];
    const float* b_ih   = (const float*)d_in[3];
    const float* b_hh   = (const float*)d_in[4];
    float* outp         = (float*)d_out;

    lstm_fused<<<dim3(128), dim3(512), 0, stream>>>(images, w_ih, w_hh, b_ih, b_hh, outp);
}